// Round 1
// baseline (666.211 us; speedup 1.0000x reference)
//
#include <hip/hip_runtime.h>
#include <hip/hip_bf16.h>
#include <hip/hip_cooperative_groups.h>
#include <math.h>

namespace cg = cooperative_groups;

typedef __bf16 bf16_t;
typedef bf16_t bf16x8 __attribute__((ext_vector_type(8)));
typedef bf16_t bf16x4 __attribute__((ext_vector_type(4)));
typedef float  f32x4  __attribute__((ext_vector_type(4)));
typedef float  vf4    __attribute__((ext_vector_type(4)));

#define HH 2048
#define BB 32
#define TT 4
#define FF 19
#define NBLK 256
#define NTHR 256

// ---- dynamic LDS layout (bytes) ----
#define LDS_WHH   0         // bf16[32][2048] swizzled : 131072
#define LDS_X     131072    // float[128][20]          : 10240
#define LDS_WIH0  141312    // float[32][20]           : 2560
#define LDS_B0    143872    // float[32]               : 128
#define LDS_B1    144000    // float[32]               : 128
#define LDS_G     144128    // float[32][33]           : 4224
#define LDS_TOTAL 148352

// ---- workspace layout (bytes) ----
// h0 bf16 [T*B][2048] : 524288
// h1 bf16 [T*B][2048] : 524288 (offset 524288)
// h1 f32  [T*B][2048] : 1048576 (offset 1048576)
// g1 f32  [T*B][256][32] : 4194304 (offset 2097152)

__device__ __forceinline__ float sigm(float x) { return 1.0f / (1.0f + expf(-x)); }

// Load 32 rows (n = gate*8+uu -> global row gate*2048 + blk*8 + uu) x 2048 f32
// -> bf16 into LDS with XOR swizzle byte ^= ((row&7)<<4) (G4: row stride 4096B is bank-aligned).
__device__ __forceinline__ void load_w_lds(char* smem, const float* __restrict__ w, int blk, int tid) {
    bf16_t* dst = (bf16_t*)(smem + LDS_WHH);
    for (int idx = tid; idx < 32 * 512; idx += NTHR) {
        int row = idx >> 9, kq = idx & 511;
        int gr = (row >> 3) * 2048 + blk * 8 + (row & 7);
        vf4 v = *reinterpret_cast<const vf4*>(w + (size_t)gr * 2048 + kq * 4);
        bf16x4 bv;
        bv[0] = (bf16_t)v[0]; bv[1] = (bf16_t)v[1]; bv[2] = (bf16_t)v[2]; bv[3] = (bf16_t)v[3];
        unsigned byte = (unsigned)(row * 4096) + (((unsigned)(kq * 8)) ^ (((unsigned)(row & 7)) << 4));
        *reinterpret_cast<bf16x4*>((char*)dst + byte) = bv;
    }
}

// gates(32x32) = h_prev(32x2048 bf16 global) @ w_lds.T ; wave -> one 16x16 quadrant.
__device__ __forceinline__ void step_gemm(const __hip_bfloat16* __restrict__ hprev,
                                          const char* smem, float* gates,
                                          int lane, int wv, int do_mfma) {
    const int mt = wv >> 1, nt = wv & 1;
    const int r = lane & 15, g4 = lane >> 4;
    f32x4 acc0 = {0.f, 0.f, 0.f, 0.f}, acc1 = {0.f, 0.f, 0.f, 0.f};
    if (do_mfma) {
        const char* bbase = smem + LDS_WHH;
        const int n = nt * 16 + r;
        const unsigned brow = (unsigned)(n * 4096);
        const unsigned bsw = ((unsigned)(n & 7)) << 4;
        const __hip_bfloat16* aptr = hprev + (mt * 16 + r) * 2048 + g4 * 8;
        #pragma unroll 4
        for (int ks = 0; ks < 64; ks += 2) {  // two acc chains to break MFMA dep latency
            bf16x8 a0 = *reinterpret_cast<const bf16x8*>(aptr + ks * 32);
            bf16x8 b0 = *reinterpret_cast<const bf16x8*>(bbase + brow + (((unsigned)(ks * 64 + g4 * 16)) ^ bsw));
            acc0 = __builtin_amdgcn_mfma_f32_16x16x32_bf16(a0, b0, acc0, 0, 0, 0);
            bf16x8 a1 = *reinterpret_cast<const bf16x8*>(aptr + (ks + 1) * 32);
            bf16x8 b1 = *reinterpret_cast<const bf16x8*>(bbase + brow + (((unsigned)((ks + 1) * 64 + g4 * 16)) ^ bsw));
            acc1 = __builtin_amdgcn_mfma_f32_16x16x32_bf16(a1, b1, acc1, 0, 0, 0);
        }
    }
    f32x4 s = acc0 + acc1;
    #pragma unroll
    for (int r2 = 0; r2 < 4; ++r2)  // D map (m89-verified): col=lane&15, row=(lane>>4)*4+reg
        gates[(mt * 16 + g4 * 4 + r2) * 33 + nt * 16 + r] = s[r2];
}

__global__ __launch_bounds__(NTHR, 1) void fused_lstm(
    const float* __restrict__ state, const float* __restrict__ action,
    const float* __restrict__ conv_w, const float* __restrict__ conv_b,
    const float* __restrict__ w_ih0, const float* __restrict__ w_hh0,
    const float* __restrict__ b_ih0, const float* __restrict__ b_hh0,
    const float* __restrict__ w_ih1, const float* __restrict__ w_hh1,
    const float* __restrict__ b_ih1, const float* __restrict__ b_hh1,
    const float* __restrict__ lin_w, const float* __restrict__ lin_b,
    float* __restrict__ out, char* __restrict__ ws)
{
    extern __shared__ char smem[];
    float* x_lds    = (float*)(smem + LDS_X);
    float* wih0_lds = (float*)(smem + LDS_WIH0);
    float* b0_lds   = (float*)(smem + LDS_B0);
    float* b1_lds   = (float*)(smem + LDS_B1);
    float* gates    = (float*)(smem + LDS_G);

    const int tid  = threadIdx.x;
    const int blk  = blockIdx.x;
    const int lane = tid & 63;
    const int wv   = tid >> 6;
    const int m    = tid >> 3;   // batch row this thread owns
    const int u    = tid & 7;    // local hidden unit this thread owns

    __hip_bfloat16* h0_ws = (__hip_bfloat16*)ws;
    __hip_bfloat16* h1_ws = (__hip_bfloat16*)(ws + 524288);
    float*          h1f   = (float*)(ws + 1048576);
    float*          g1    = (float*)(ws + 2097152);

    cg::grid_group gg = cg::this_grid();

    // ---------- prep: x = tanh(cw*concat(state,action)+cb) into LDS ----------
    {
        float cw = conv_w[0], cb = conv_b[0];
        for (int i = tid; i < TT * BB * FF; i += NTHR) {
            int f = i % FF; int tb = i / FF; int t = tb >> 5; int mm = tb & 31;
            float v = (f < 15) ? state[(mm * TT + t) * 15 + f] : action[(mm * TT + t) * 4 + (f - 15)];
            x_lds[tb * 20 + f] = tanhf(cw * v + cb);
        }
        for (int i = tid; i < 32 * FF; i += NTHR) {
            int n = i / FF; int f = i % FF;
            int gr = (n >> 3) * 2048 + blk * 8 + (n & 7);
            wih0_lds[n * 20 + f] = w_ih0[(size_t)gr * FF + f];
        }
        if (tid < 32) {
            int gr = (tid >> 3) * 2048 + blk * 8 + (tid & 7);
            b0_lds[tid] = b_ih0[gr] + b_hh0[gr];
        }
    }
    load_w_lds(smem, w_hh0, blk, tid);  // w_hh0 slice, read from HBM exactly once
    __syncthreads();

    // ---------- layer 0 recurrence ----------
    float c0 = 0.f;
    for (int t = 0; t < TT; ++t) {
        const __hip_bfloat16* hp = (t > 0) ? (h0_ws + (size_t)(t - 1) * BB * HH) : h0_ws;
        step_gemm(hp, smem, gates, lane, wv, t > 0);
        __syncthreads();
        float gv[4];
        #pragma unroll
        for (int gate = 0; gate < 4; ++gate) {
            int n = gate * 8 + u;
            float a = gates[m * 33 + n] + b0_lds[n];
            const float* xr = &x_lds[(t * 32 + m) * 20];
            const float* wr = &wih0_lds[n * 20];
            #pragma unroll
            for (int f = 0; f < FF; ++f) a += xr[f] * wr[f];
            gv[gate] = a;
        }
        float ig = sigm(gv[0]), fg = sigm(gv[1]), g2 = tanhf(gv[2]), og = sigm(gv[3]);
        c0 = fg * c0 + ig * g2;
        float hval = og * tanhf(c0);
        h0_ws[(size_t)(t * 32 + m) * 2048 + blk * 8 + u] = __float2bfloat16(hval);
        gg.sync();
    }

    // ---------- layer-1 input GEMM: g1 = H0(128x2048) @ w_ih1_slice.T + bias1 (block-local) ----------
    load_w_lds(smem, w_ih1, blk, tid);
    if (tid < 32) {
        int gr = (tid >> 3) * 2048 + blk * 8 + (tid & 7);
        b1_lds[tid] = b_ih1[gr] + b_hh1[gr];
    }
    __syncthreads();
    {
        const int r = lane & 15, g4 = lane >> 4;
        const char* bbase = smem + LDS_WHH;
        const unsigned bsw0 = ((unsigned)(r & 7)) << 4;       // n0 = r
        const unsigned bsw1 = ((unsigned)((16 + r) & 7)) << 4; // n1 = 16+r (same low bits)
        #pragma unroll
        for (int mi = 0; mi < 2; ++mi) {
            int mt = wv * 2 + mi;
            f32x4 acc0 = {0.f, 0.f, 0.f, 0.f}, acc1 = {0.f, 0.f, 0.f, 0.f};
            const __hip_bfloat16* aptr = h0_ws + (size_t)(mt * 16 + r) * 2048 + g4 * 8;
            #pragma unroll 4
            for (int ks = 0; ks < 64; ++ks) {
                bf16x8 a  = *reinterpret_cast<const bf16x8*>(aptr + ks * 32);
                bf16x8 b0 = *reinterpret_cast<const bf16x8*>(bbase + (unsigned)(r * 4096)        + (((unsigned)(ks * 64 + g4 * 16)) ^ bsw0));
                bf16x8 b1 = *reinterpret_cast<const bf16x8*>(bbase + (unsigned)((16 + r) * 4096) + (((unsigned)(ks * 64 + g4 * 16)) ^ bsw1));
                acc0 = __builtin_amdgcn_mfma_f32_16x16x32_bf16(a, b0, acc0, 0, 0, 0);
                acc1 = __builtin_amdgcn_mfma_f32_16x16x32_bf16(a, b1, acc1, 0, 0, 0);
            }
            #pragma unroll
            for (int r2 = 0; r2 < 4; ++r2) {
                int tb = mt * 16 + g4 * 4 + r2;
                g1[((size_t)tb * 256 + blk) * 32 + r]      = acc0[r2] + b1_lds[r];
                g1[((size_t)tb * 256 + blk) * 32 + 16 + r] = acc1[r2] + b1_lds[16 + r];
            }
        }
    }
    __threadfence();   // make own-block g1 stores visible to own later reads
    __syncthreads();
    load_w_lds(smem, w_hh1, blk, tid);  // w_hh1 slice, HBM once
    __syncthreads();

    // ---------- layer 1 recurrence ----------
    float c1 = 0.f;
    for (int t = 0; t < TT; ++t) {
        const __hip_bfloat16* hp = (t > 0) ? (h1_ws + (size_t)(t - 1) * BB * HH) : h1_ws;
        step_gemm(hp, smem, gates, lane, wv, t > 0);
        __syncthreads();
        float gv[4];
        #pragma unroll
        for (int gate = 0; gate < 4; ++gate) {
            int n = gate * 8 + u;
            gv[gate] = gates[m * 33 + n] + g1[((size_t)(t * 32 + m) * 256 + blk) * 32 + n];
        }
        float ig = sigm(gv[0]), fg = sigm(gv[1]), g2 = tanhf(gv[2]), og = sigm(gv[3]);
        c1 = fg * c1 + ig * g2;
        float hval = og * tanhf(c1);
        size_t oidx = (size_t)(t * 32 + m) * 2048 + blk * 8 + u;
        h1_ws[oidx] = __float2bfloat16(hval);
        h1f[oidx] = hval;
        gg.sync();
    }

    // ---------- final linear + sigmoid: out[b] = sig(sum_{t,u} h1[t][b][u]*lin_w[t*2048+u] + lin_b) ----------
    if (blk < BB) {
        float part = 0.f;
        for (int k = tid; k < 4 * HH; k += NTHR) {
            int t = k >> 11, uu = k & 2047;
            part += h1f[(size_t)(t * 32 + blk) * 2048 + uu] * lin_w[k];
        }
        #pragma unroll
        for (int off = 32; off; off >>= 1) part += __shfl_down(part, off, 64);
        if (lane == 0) gates[wv] = part;
        __syncthreads();
        if (tid == 0) {
            float s = gates[0] + gates[1] + gates[2] + gates[3] + lin_b[0];
            out[blk] = 1.f / (1.f + expf(-s));
        }
    }
}

extern "C" void kernel_launch(void* const* d_in, const int* in_sizes, int n_in,
                              void* d_out, int out_size, void* d_ws, size_t ws_size,
                              hipStream_t stream) {
    const float* state  = (const float*)d_in[0];
    const float* action = (const float*)d_in[1];
    const float* conv_w = (const float*)d_in[2];
    const float* conv_b = (const float*)d_in[3];
    const float* w_ih0  = (const float*)d_in[4];
    const float* w_hh0  = (const float*)d_in[5];
    const float* b_ih0  = (const float*)d_in[6];
    const float* b_hh0  = (const float*)d_in[7];
    const float* w_ih1  = (const float*)d_in[8];
    const float* w_hh1  = (const float*)d_in[9];
    const float* b_ih1  = (const float*)d_in[10];
    const float* b_hh1  = (const float*)d_in[11];
    const float* lin_w  = (const float*)d_in[12];
    const float* lin_b  = (const float*)d_in[13];
    float* out = (float*)d_out;
    char*  ws  = (char*)d_ws;

    void* args[] = {&state, &action, &conv_w, &conv_b, &w_ih0, &w_hh0, &b_ih0, &b_hh0,
                    &w_ih1, &w_hh1, &b_ih1, &b_hh1, &lin_w, &lin_b, &out, &ws};
    hipLaunchCooperativeKernel((void*)fused_lstm, dim3(NBLK), dim3(NTHR), args,
                               LDS_TOTAL, stream);
}

// Round 2
// 469.882 us; speedup vs baseline: 1.4178x; 1.4178x over previous
//
#include <hip/hip_runtime.h>
#include <hip/hip_bf16.h>
#include <math.h>

typedef __bf16 bf16_t;
typedef bf16_t bf16x8 __attribute__((ext_vector_type(8)));
typedef bf16_t bf16x4 __attribute__((ext_vector_type(4)));
typedef float  f32x4  __attribute__((ext_vector_type(4)));
typedef float  vf4    __attribute__((ext_vector_type(4)));

#define HH 2048
#define BB 32
#define TT 4
#define FF 19
#define NBLK 256
#define NTHR 512

// ---- dynamic LDS layout (bytes) ----
#define LDS_WHH   0         // bf16[32][2048] swizzled : 131072
#define LDS_X     131072    // float[128][20]          : 10240
#define LDS_WIH0  141312    // float[32][20]           : 2560
#define LDS_B0    143872    // float[32]               : 128
#define LDS_B1    144000    // float[32]               : 128
#define LDS_GP    144128    // float[2][32][33]        : 8448
#define LDS_RED   152576    // float[8]                : 32
#define LDS_TOTAL 152608

// ---- workspace layout (bytes) ----
#define WS_BAR    0         // barrier slots: 12 x 1024 B (memset to 0 each launch)
#define BAR_BYTES 16384
#define WS_H0     16384     // bf16 [T*B][2048] : 524288
#define WS_H1     540672    // bf16 [T*B][2048] : 524288
#define WS_G1     1064960   // f32 [128][256][32] : 4194304  (end 5259264)

__device__ __forceinline__ float sigm(float x) { return 1.0f / (1.0f + expf(-x)); }

// Two-level one-shot grid barrier. Slot layout (unsigned words):
// leaf[g] at +g*16, root at +128, flag at +144. Zeroed by memset before launch.
__device__ __forceinline__ void gbar(char* barbase, int slot, int blk) {
    __syncthreads();
    if (threadIdx.x == 0) {
        unsigned* base = (unsigned*)(barbase + slot * 1024);
        unsigned* leaf = base + (blk & 7) * 16;
        unsigned* root = base + 128;
        unsigned* flag = base + 144;
        __threadfence();  // release this block's global stores
        if (__hip_atomic_fetch_add(leaf, 1u, __ATOMIC_RELAXED, __HIP_MEMORY_SCOPE_AGENT) == 31u) {
            if (__hip_atomic_fetch_add(root, 1u, __ATOMIC_RELAXED, __HIP_MEMORY_SCOPE_AGENT) == 7u) {
                __hip_atomic_store(flag, 1u, __ATOMIC_RELAXED, __HIP_MEMORY_SCOPE_AGENT);
            }
        }
        while (__hip_atomic_load(flag, __ATOMIC_RELAXED, __HIP_MEMORY_SCOPE_AGENT) == 0u) {
            __builtin_amdgcn_s_sleep(2);
        }
        __threadfence();  // acquire: invalidate caches before reading others' stores
    }
    __syncthreads();
}

// Load 32 gate-rows x 2048 f32 -> bf16 LDS, XOR-swizzled byte ^= ((row&7)<<4).
// 512 threads: one full 8KB row per pass, 8 rows batched -> 8 outstanding loads/thread.
__device__ __forceinline__ void load_w_lds(char* smem, const float* __restrict__ w, int blk, int tid) {
    char* dst = smem + LDS_WHH;
    #pragma unroll 1
    for (int base = 0; base < 32; base += 8) {
        vf4 v[8];
        #pragma unroll
        for (int j = 0; j < 8; ++j) {
            int row = base + j;
            int gr = (row >> 3) * 2048 + blk * 8 + (row & 7);
            v[j] = *reinterpret_cast<const vf4*>(w + (size_t)gr * 2048 + tid * 4);
        }
        #pragma unroll
        for (int j = 0; j < 8; ++j) {
            int row = base + j;
            bf16x4 bv;
            bv[0] = (bf16_t)v[j][0]; bv[1] = (bf16_t)v[j][1];
            bv[2] = (bf16_t)v[j][2]; bv[3] = (bf16_t)v[j][3];
            unsigned byte = (unsigned)(row * 4096) + (((unsigned)(tid * 8)) ^ (((unsigned)(row & 7)) << 4));
            *reinterpret_cast<bf16x4*>(dst + byte) = bv;
        }
    }
}

// gates(32x32) = h_prev(32x2048 bf16 global) @ w_lds.T, 8 waves:
// wave = quadrant(2b) x K-half(1b); partial sums land in gparts[2][32][33].
__device__ __forceinline__ void step_gemm(const __hip_bfloat16* __restrict__ hprev,
                                          const char* smem, float* gparts,
                                          int lane, int wv, int do_mfma) {
    const int q  = wv >> 1;
    const int kh = wv & 1;
    const int mt = q >> 1, nt = q & 1;
    const int r = lane & 15, g4 = lane >> 4;
    f32x4 acc0 = {0.f,0.f,0.f,0.f}, acc1 = {0.f,0.f,0.f,0.f};
    if (do_mfma) {
        const char* bbase = smem + LDS_WHH;
        const int n = nt * 16 + r;
        const unsigned brow = (unsigned)(n * 4096);
        const unsigned bsw = ((unsigned)(n & 7)) << 4;
        const __hip_bfloat16* aptr = hprev + (mt * 16 + r) * 2048 + g4 * 8;
        const int k0 = kh * 32;
        #pragma unroll
        for (int ks = 0; ks < 32; ks += 2) {
            int ka = k0 + ks, kb = k0 + ks + 1;
            bf16x8 a0 = *reinterpret_cast<const bf16x8*>(aptr + ka * 32);
            bf16x8 b0 = *reinterpret_cast<const bf16x8*>(bbase + brow + (((unsigned)(ka * 64 + g4 * 16)) ^ bsw));
            acc0 = __builtin_amdgcn_mfma_f32_16x16x32_bf16(a0, b0, acc0, 0, 0, 0);
            bf16x8 a1 = *reinterpret_cast<const bf16x8*>(aptr + kb * 32);
            bf16x8 b1 = *reinterpret_cast<const bf16x8*>(bbase + brow + (((unsigned)(kb * 64 + g4 * 16)) ^ bsw));
            acc1 = __builtin_amdgcn_mfma_f32_16x16x32_bf16(a1, b1, acc1, 0, 0, 0);
        }
    }
    f32x4 s = acc0 + acc1;
    #pragma unroll
    for (int r2 = 0; r2 < 4; ++r2)  // D map: col=lane&15, row=(lane>>4)*4+reg
        gparts[(kh * 32 + mt * 16 + g4 * 4 + r2) * 33 + nt * 16 + r] = s[r2];
}

__global__ __launch_bounds__(NTHR, 2) void fused_lstm(
    const float* __restrict__ state, const float* __restrict__ action,
    const float* __restrict__ conv_w, const float* __restrict__ conv_b,
    const float* __restrict__ w_ih0, const float* __restrict__ w_hh0,
    const float* __restrict__ b_ih0, const float* __restrict__ b_hh0,
    const float* __restrict__ w_ih1, const float* __restrict__ w_hh1,
    const float* __restrict__ b_ih1, const float* __restrict__ b_hh1,
    const float* __restrict__ lin_w, const float* __restrict__ lin_b,
    float* __restrict__ out, char* __restrict__ ws)
{
    extern __shared__ char smem[];
    float* x_lds    = (float*)(smem + LDS_X);
    float* wih0_lds = (float*)(smem + LDS_WIH0);
    float* b0_lds   = (float*)(smem + LDS_B0);
    float* b1_lds   = (float*)(smem + LDS_B1);
    float* gparts   = (float*)(smem + LDS_GP);
    float* red      = (float*)(smem + LDS_RED);

    const int tid  = threadIdx.x;
    const int blk  = blockIdx.x;
    const int lane = tid & 63;
    const int wv   = tid >> 6;
    const int m    = tid >> 3;   // (tid<256) batch row owned in gate phase
    const int u    = tid & 7;    // (tid<256) local hidden unit owned

    __hip_bfloat16* h0_ws = (__hip_bfloat16*)(ws + WS_H0);
    __hip_bfloat16* h1_ws = (__hip_bfloat16*)(ws + WS_H1);
    float*          g1    = (float*)(ws + WS_G1);

    // ---------- prep: x = tanh(cw*concat(state,action)+cb) ----------
    {
        float cw = conv_w[0], cb = conv_b[0];
        for (int i = tid; i < TT * BB * FF; i += NTHR) {
            int f = i % FF; int tb = i / FF; int t = tb >> 5; int mm = tb & 31;
            float v = (f < 15) ? state[(mm * TT + t) * 15 + f] : action[(mm * TT + t) * 4 + (f - 15)];
            x_lds[tb * 20 + f] = tanhf(cw * v + cb);
        }
        for (int i = tid; i < 32 * FF; i += NTHR) {
            int n = i / FF; int f = i % FF;
            int gr = (n >> 3) * 2048 + blk * 8 + (n & 7);
            wih0_lds[n * 20 + f] = w_ih0[(size_t)gr * FF + f];
        }
        if (tid < 32) {
            int gr = (tid >> 3) * 2048 + blk * 8 + (tid & 7);
            b0_lds[tid] = b_ih0[gr] + b_hh0[gr];
        }
    }
    load_w_lds(smem, w_hh0, blk, tid);  // w_hh0 slice: HBM exactly once
    __syncthreads();

    // ---------- layer 0 recurrence ----------
    float c0 = 0.f;
    for (int t = 0; t < TT; ++t) {
        const __hip_bfloat16* hp = h0_ws + (size_t)((t > 0 ? t - 1 : 0) * BB * HH);
        step_gemm(hp, smem, gparts, lane, wv, t > 0);
        __syncthreads();
        if (tid < 256) {
            float gv[4];
            #pragma unroll
            for (int gate = 0; gate < 4; ++gate) {
                int n = gate * 8 + u;
                float a = gparts[m * 33 + n] + gparts[(32 + m) * 33 + n] + b0_lds[n];
                const float* xr = &x_lds[(t * 32 + m) * 20];
                const float* wr = &wih0_lds[n * 20];
                #pragma unroll
                for (int f = 0; f < FF; ++f) a += xr[f] * wr[f];
                gv[gate] = a;
            }
            float ig = sigm(gv[0]), fg = sigm(gv[1]), g2 = tanhf(gv[2]), og = sigm(gv[3]);
            c0 = fg * c0 + ig * g2;
            h0_ws[(size_t)(t * 32 + m) * 2048 + blk * 8 + u] = __float2bfloat16(og * tanhf(c0));
        }
        gbar(ws, t, blk);   // slots 0..3
    }

    // ---------- layer-1 input GEMM: g1 = H0(128x2048) @ w_ih1_slice.T + bias1 ----------
    load_w_lds(smem, w_ih1, blk, tid);
    if (tid < 32) {
        int gr = (tid >> 3) * 2048 + blk * 8 + (tid & 7);
        b1_lds[tid] = b_ih1[gr] + b_hh1[gr];
    }
    __syncthreads();
    {
        const int r = lane & 15, g4 = lane >> 4;
        const char* bbase = smem + LDS_WHH;
        const unsigned bsw0 = ((unsigned)(r & 7)) << 4;   // rows r and 16+r share (row&7)
        const int mt = wv;                                 // 8 waves -> 8 m-tiles of 16
        f32x4 acc0 = {0.f,0.f,0.f,0.f}, acc1 = {0.f,0.f,0.f,0.f};
        const __hip_bfloat16* aptr = h0_ws + (size_t)(mt * 16 + r) * 2048 + g4 * 8;
        #pragma unroll 4
        for (int ks = 0; ks < 64; ++ks) {
            bf16x8 a  = *reinterpret_cast<const bf16x8*>(aptr + ks * 32);
            bf16x8 b0 = *reinterpret_cast<const bf16x8*>(bbase + (unsigned)(r * 4096)        + (((unsigned)(ks * 64 + g4 * 16)) ^ bsw0));
            bf16x8 b1 = *reinterpret_cast<const bf16x8*>(bbase + (unsigned)((16 + r) * 4096) + (((unsigned)(ks * 64 + g4 * 16)) ^ bsw0));
            acc0 = __builtin_amdgcn_mfma_f32_16x16x32_bf16(a, b0, acc0, 0, 0, 0);
            acc1 = __builtin_amdgcn_mfma_f32_16x16x32_bf16(a, b1, acc1, 0, 0, 0);
        }
        #pragma unroll
        for (int r2 = 0; r2 < 4; ++r2) {
            int tb = mt * 16 + g4 * 4 + r2;
            g1[((size_t)tb * 256 + blk) * 32 + r]      = acc0[r2] + b1_lds[r];
            g1[((size_t)tb * 256 + blk) * 32 + 16 + r] = acc1[r2] + b1_lds[16 + r];
        }
    }
    __threadfence();   // own-block g1 stores -> own later loads
    __syncthreads();
    load_w_lds(smem, w_hh1, blk, tid);  // w_hh1 slice: HBM once
    __syncthreads();

    // ---------- layer 1 recurrence ----------
    float c1 = 0.f;
    for (int t = 0; t < TT; ++t) {
        const __hip_bfloat16* hp = h1_ws + (size_t)((t > 0 ? t - 1 : 0) * BB * HH);
        step_gemm(hp, smem, gparts, lane, wv, t > 0);
        __syncthreads();
        if (tid < 256) {
            float gv[4];
            #pragma unroll
            for (int gate = 0; gate < 4; ++gate) {
                int n = gate * 8 + u;
                gv[gate] = gparts[m * 33 + n] + gparts[(32 + m) * 33 + n]
                         + g1[((size_t)(t * 32 + m) * 256 + blk) * 32 + n];
            }
            float ig = sigm(gv[0]), fg = sigm(gv[1]), g2 = tanhf(gv[2]), og = sigm(gv[3]);
            c1 = fg * c1 + ig * g2;
            h1_ws[(size_t)(t * 32 + m) * 2048 + blk * 8 + u] = __float2bfloat16(og * tanhf(c1));
        }
        gbar(ws, 4 + t, blk);   // slots 4..7
    }

    // ---------- final linear + sigmoid ----------
    if (blk < BB) {
        float part = 0.f;
        for (int i = tid; i < 1024; i += NTHR) {     // 1024 chunks of 8 bf16
            int k = i * 8; int t = k >> 11; int uu = k & 2047;
            uint4 hv = *reinterpret_cast<const uint4*>(h1_ws + (size_t)(t * 32 + blk) * 2048 + uu);
            const float* lw = lin_w + k;
            #pragma unroll
            for (int j = 0; j < 4; ++j) {
                unsigned wj = (&hv.x)[j];
                float lo = __uint_as_float(wj << 16);
                float hi = __uint_as_float(wj & 0xffff0000u);
                part += lo * lw[2 * j] + hi * lw[2 * j + 1];
            }
        }
        #pragma unroll
        for (int off = 32; off; off >>= 1) part += __shfl_down(part, off, 64);
        if (lane == 0) red[wv] = part;
        __syncthreads();
        if (tid == 0) {
            float s = red[0] + red[1] + red[2] + red[3] + red[4] + red[5] + red[6] + red[7] + lin_b[0];
            out[blk] = 1.f / (1.f + expf(-s));
        }
    }
}

extern "C" void kernel_launch(void* const* d_in, const int* in_sizes, int n_in,
                              void* d_out, int out_size, void* d_ws, size_t ws_size,
                              hipStream_t stream) {
    const float* state  = (const float*)d_in[0];
    const float* action = (const float*)d_in[1];
    const float* conv_w = (const float*)d_in[2];
    const float* conv_b = (const float*)d_in[3];
    const float* w_ih0  = (const float*)d_in[4];
    const float* w_hh0  = (const float*)d_in[5];
    const float* b_ih0  = (const float*)d_in[6];
    const float* b_hh0  = (const float*)d_in[7];
    const float* w_ih1  = (const float*)d_in[8];
    const float* w_hh1  = (const float*)d_in[9];
    const float* b_ih1  = (const float*)d_in[10];
    const float* b_hh1  = (const float*)d_in[11];
    const float* lin_w  = (const float*)d_in[12];
    const float* lin_b  = (const float*)d_in[13];
    float* out = (float*)d_out;
    char*  ws  = (char*)d_ws;

    hipMemsetAsync(ws, 0, BAR_BYTES, stream);   // zero barrier slots (graph-capturable)

    void* args[] = {&state, &action, &conv_w, &conv_b, &w_ih0, &w_hh0, &b_ih0, &b_hh0,
                    &w_ih1, &w_hh1, &b_ih1, &b_hh1, &lin_w, &lin_b, &out, &ws};
    hipLaunchCooperativeKernel((void*)fused_lstm, dim3(NBLK), dim3(NTHR), args,
                               LDS_TOTAL, stream);
}

// Round 3
// 352.262 us; speedup vs baseline: 1.8912x; 1.3339x over previous
//
#include <hip/hip_runtime.h>
#include <hip/hip_bf16.h>
#include <math.h>

typedef __bf16 bf16_t;
typedef bf16_t bf16x8 __attribute__((ext_vector_type(8)));
typedef bf16_t bf16x4 __attribute__((ext_vector_type(4)));
typedef float  f32x4  __attribute__((ext_vector_type(4)));
typedef float  vf4    __attribute__((ext_vector_type(4)));

#define HH 2048
#define BB 32
#define TT 4
#define FF 19
#define NBLK 256
#define NTHR 512

// ---- dynamic LDS layout (bytes) ----
#define LDS_WHH   0         // bf16[32][2048] swizzled : 131072
#define LDS_X     131072    // float[128][20]          : 10240
#define LDS_WIH0  141312    // float[32][20]           : 2560
#define LDS_B0    143872    // float[32]               : 128
#define LDS_B1    144000    // float[32]               : 128
#define LDS_GP    144128    // float[2][32][33]        : 8448
#define LDS_RED   152576    // float[8]                : 32
#define LDS_TOTAL 152608

// ---- workspace layout (bytes) ----
#define WS_BAR    0         // barrier slots: 8 x 1024 B + guard pad (memset 0 each launch)
#define BAR_BYTES 16384
#define WS_H0     16384     // bf16 [T*B][2048] : 524288
#define WS_H1     540672    // bf16 [T*B][2048] : 524288
#define WS_G1     1064960   // f32 [128][256][32] : 4194304  (end 5259264)

__device__ __forceinline__ float sigm(float x) { return 1.0f / (1.0f + expf(-x)); }

// ---- fence-free two-level grid barrier ----
// No __threadfence: h-stores are write-through agent atomics (drained by the
// vmcnt(0) __syncthreads emits), and no XCD ever caches an h-line before its
// barrier (kernel starts acquire-clean; h regions are per-t disjoint, written
// once, read only post-barrier) -> no stale L2 copies can exist.
__device__ __forceinline__ void gbar_arrive(char* barbase, int slot, int blk) {
    __syncthreads();   // all threads' stores drained (compiler emits vmcnt(0))
    if (threadIdx.x == 0) {
        unsigned* base = (unsigned*)(barbase + slot * 1024);
        if (__hip_atomic_fetch_add(base + (blk & 7) * 16, 1u, __ATOMIC_RELAXED, __HIP_MEMORY_SCOPE_AGENT) == 31u)
            if (__hip_atomic_fetch_add(base + 128, 1u, __ATOMIC_RELAXED, __HIP_MEMORY_SCOPE_AGENT) == 7u)
                __hip_atomic_store(base + 144, 1u, __ATOMIC_RELAXED, __HIP_MEMORY_SCOPE_AGENT);
    }
}
__device__ __forceinline__ void gbar_wait(char* barbase, int slot) {
    if (threadIdx.x == 0) {
        unsigned* flag = (unsigned*)(barbase + slot * 1024) + 144;
        while (__hip_atomic_load(flag, __ATOMIC_RELAXED, __HIP_MEMORY_SCOPE_AGENT) == 0u)
            __builtin_amdgcn_s_sleep(1);
    }
    __syncthreads();
}

// Touch (prefetch into L3/L2) two 8-row groups (2 x 64KB) of this block's
// future weight slice; dummy-accumulate so loads aren't DCE'd.
__device__ __forceinline__ float touch2(const float* __restrict__ w, int blk, int r0, int tid) {
    float acc = 0.f;
    #pragma unroll
    for (int rg = 0; rg < 2; ++rg) {
        const float* p = w + ((size_t)((r0 + rg) * 2048 + blk * 8)) * 2048;
        #pragma unroll
        for (int j = 0; j < 8; ++j) {
            vf4 v = *reinterpret_cast<const vf4*>(p + j * 2048 + tid * 4);
            acc += v[0] + v[1] + v[2] + v[3];
        }
    }
    return acc;
}

// Load 32 gate-rows x 2048 f32 -> bf16 LDS, XOR-swizzled byte ^= ((row&7)<<4).
__device__ __forceinline__ void load_w_lds(char* smem, const float* __restrict__ w, int blk, int tid) {
    char* dst = smem + LDS_WHH;
    #pragma unroll 1
    for (int base = 0; base < 32; base += 8) {
        vf4 v[8];
        #pragma unroll
        for (int j = 0; j < 8; ++j) {
            int row = base + j;
            int gr = (row >> 3) * 2048 + blk * 8 + (row & 7);
            v[j] = *reinterpret_cast<const vf4*>(w + (size_t)gr * 2048 + tid * 4);
        }
        #pragma unroll
        for (int j = 0; j < 8; ++j) {
            int row = base + j;
            bf16x4 bv;
            bv[0] = (bf16_t)v[j][0]; bv[1] = (bf16_t)v[j][1];
            bv[2] = (bf16_t)v[j][2]; bv[3] = (bf16_t)v[j][3];
            unsigned byte = (unsigned)(row * 4096) + (((unsigned)(tid * 8)) ^ (((unsigned)(row & 7)) << 4));
            *reinterpret_cast<bf16x4*>(dst + byte) = bv;
        }
    }
}

// gates(32x32) = h_prev(32x2048 bf16 global, plain cached loads) @ w_lds.T
// 8 waves: wave = quadrant(2b) x K-half(1b); partials -> gparts[2][32][33].
__device__ __forceinline__ void step_gemm(const __hip_bfloat16* __restrict__ hprev,
                                          const char* smem, float* gparts,
                                          int lane, int wv, int do_mfma) {
    const int q  = wv >> 1;
    const int kh = wv & 1;
    const int mt = q >> 1, nt = q & 1;
    const int r = lane & 15, g4 = lane >> 4;
    f32x4 acc0 = {0.f,0.f,0.f,0.f}, acc1 = {0.f,0.f,0.f,0.f};
    if (do_mfma) {
        const char* bbase = smem + LDS_WHH;
        const int n = nt * 16 + r;
        const unsigned brow = (unsigned)(n * 4096);
        const unsigned bsw = ((unsigned)(n & 7)) << 4;
        const __hip_bfloat16* aptr = hprev + (mt * 16 + r) * 2048 + g4 * 8;
        const int k0 = kh * 32;
        #pragma unroll
        for (int ks = 0; ks < 32; ks += 2) {
            int ka = k0 + ks, kb = k0 + ks + 1;
            bf16x8 a0 = *reinterpret_cast<const bf16x8*>(aptr + ka * 32);
            bf16x8 b0 = *reinterpret_cast<const bf16x8*>(bbase + brow + (((unsigned)(ka * 64 + g4 * 16)) ^ bsw));
            acc0 = __builtin_amdgcn_mfma_f32_16x16x32_bf16(a0, b0, acc0, 0, 0, 0);
            bf16x8 a1 = *reinterpret_cast<const bf16x8*>(aptr + kb * 32);
            bf16x8 b1 = *reinterpret_cast<const bf16x8*>(bbase + brow + (((unsigned)(kb * 64 + g4 * 16)) ^ bsw));
            acc1 = __builtin_amdgcn_mfma_f32_16x16x32_bf16(a1, b1, acc1, 0, 0, 0);
        }
    }
    f32x4 s = acc0 + acc1;
    #pragma unroll
    for (int r2 = 0; r2 < 4; ++r2)  // D map: col=lane&15, row=(lane>>4)*4+reg
        gparts[(kh * 32 + mt * 16 + g4 * 4 + r2) * 33 + nt * 16 + r] = s[r2];
}

// write-through agent-scope bf16 store (global_store_short sc1)
__device__ __forceinline__ void store_h(__hip_bfloat16* p, float x) {
    __hip_bfloat16 hv = __float2bfloat16(x);
    unsigned short bits = *reinterpret_cast<unsigned short*>(&hv);
    __hip_atomic_store((unsigned short*)p, bits, __ATOMIC_RELAXED, __HIP_MEMORY_SCOPE_AGENT);
}

__global__ __launch_bounds__(NTHR, 2) void fused_lstm(
    const float* __restrict__ state, const float* __restrict__ action,
    const float* __restrict__ conv_w, const float* __restrict__ conv_b,
    const float* __restrict__ w_ih0, const float* __restrict__ w_hh0,
    const float* __restrict__ b_ih0, const float* __restrict__ b_hh0,
    const float* __restrict__ w_ih1, const float* __restrict__ w_hh1,
    const float* __restrict__ b_ih1, const float* __restrict__ b_hh1,
    const float* __restrict__ lin_w, const float* __restrict__ lin_b,
    float* __restrict__ out, char* __restrict__ ws)
{
    extern __shared__ char smem[];
    float* x_lds    = (float*)(smem + LDS_X);
    float* wih0_lds = (float*)(smem + LDS_WIH0);
    float* b0_lds   = (float*)(smem + LDS_B0);
    float* b1_lds   = (float*)(smem + LDS_B1);
    float* gparts   = (float*)(smem + LDS_GP);
    float* red      = (float*)(smem + LDS_RED);

    const int tid  = threadIdx.x;
    const int blk  = blockIdx.x;
    const int lane = tid & 63;
    const int wv   = tid >> 6;
    const int m    = tid >> 3;   // (tid<256) batch row owned in gate phase
    const int u    = tid & 7;    // (tid<256) local hidden unit owned

    __hip_bfloat16* h0_ws = (__hip_bfloat16*)(ws + WS_H0);
    __hip_bfloat16* h1_ws = (__hip_bfloat16*)(ws + WS_H1);
    float*          g1    = (float*)(ws + WS_G1);

    float tacc = 0.f;  // touch sink

    // ---------- prep: x = tanh(cw*concat(state,action)+cb) ----------
    {
        float cw = conv_w[0], cb = conv_b[0];
        for (int i = tid; i < TT * BB * FF; i += NTHR) {
            int f = i % FF; int tb = i / FF; int t = tb >> 5; int mm = tb & 31;
            float v = (f < 15) ? state[(mm * TT + t) * 15 + f] : action[(mm * TT + t) * 4 + (f - 15)];
            x_lds[tb * 20 + f] = tanhf(cw * v + cb);
        }
        for (int i = tid; i < 32 * FF; i += NTHR) {
            int n = i / FF; int f = i % FF;
            int gr = (n >> 3) * 2048 + blk * 8 + (n & 7);
            wih0_lds[n * 20 + f] = w_ih0[(size_t)gr * FF + f];
        }
        if (tid < 32) {
            int gr = (tid >> 3) * 2048 + blk * 8 + (tid & 7);
            b0_lds[tid] = b_ih0[gr] + b_hh0[gr];
        }
    }
    load_w_lds(smem, w_hh0, blk, tid);  // w_hh0 slice: HBM exactly once
    __syncthreads();

    // ---------- layer 0 recurrence (+ w_ih1/w_hh1 L3 prefetch in barrier slack) ----------
    float c0 = 0.f;
    for (int t = 0; t < TT; ++t) {
        const __hip_bfloat16* hp = h0_ws + (size_t)((t > 0 ? t - 1 : 0) * BB * HH);
        step_gemm(hp, smem, gparts, lane, wv, t > 0);
        __syncthreads();
        if (tid < 256) {
            float gv[4];
            #pragma unroll
            for (int gate = 0; gate < 4; ++gate) {
                int n = gate * 8 + u;
                float a = gparts[m * 33 + n] + gparts[(32 + m) * 33 + n] + b0_lds[n];
                const float* xr = &x_lds[(t * 32 + m) * 20];
                const float* wr = &wih0_lds[n * 20];
                #pragma unroll
                for (int f = 0; f < FF; ++f) a += xr[f] * wr[f];
                gv[gate] = a;
            }
            float ig = sigm(gv[0]), fg = sigm(gv[1]), g2 = tanhf(gv[2]), og = sigm(gv[3]);
            c0 = fg * c0 + ig * g2;
            store_h(h0_ws + (size_t)(t * 32 + m) * 2048 + blk * 8 + u, og * tanhf(c0));
        }
        gbar_arrive(ws, t, blk);
        tacc += touch2((t < 2) ? w_ih1 : w_hh1, blk, (t & 1) * 2, tid);  // prefetch during wait
        gbar_wait(ws, t);
    }
    if (tacc == 1.2345e30f) ((float*)(ws + 15 * 1024))[tid] = tacc;  // never true; keeps touches live

    // ---------- layer-1 input GEMM: g1 = H0(128x2048) @ w_ih1_slice.T + bias1 ----------
    load_w_lds(smem, w_ih1, blk, tid);   // L3-warm after touch
    if (tid < 32) {
        int gr = (tid >> 3) * 2048 + blk * 8 + (tid & 7);
        b1_lds[tid] = b_ih1[gr] + b_hh1[gr];
    }
    __syncthreads();
    {
        const int r = lane & 15, g4 = lane >> 4;
        const char* bbase = smem + LDS_WHH;
        const unsigned bsw0 = ((unsigned)(r & 7)) << 4;   // rows r and 16+r share (row&7)
        const int mt = wv;                                 // 8 waves -> 8 m-tiles of 16
        f32x4 acc0 = {0.f,0.f,0.f,0.f}, acc1 = {0.f,0.f,0.f,0.f};
        const __hip_bfloat16* aptr = h0_ws + (size_t)(mt * 16 + r) * 2048 + g4 * 8;
        #pragma unroll 4
        for (int ks = 0; ks < 64; ++ks) {
            bf16x8 a  = *reinterpret_cast<const bf16x8*>(aptr + ks * 32);
            bf16x8 b0 = *reinterpret_cast<const bf16x8*>(bbase + (unsigned)(r * 4096)        + (((unsigned)(ks * 64 + g4 * 16)) ^ bsw0));
            bf16x8 b1 = *reinterpret_cast<const bf16x8*>(bbase + (unsigned)((16 + r) * 4096) + (((unsigned)(ks * 64 + g4 * 16)) ^ bsw0));
            acc0 = __builtin_amdgcn_mfma_f32_16x16x32_bf16(a, b0, acc0, 0, 0, 0);
            acc1 = __builtin_amdgcn_mfma_f32_16x16x32_bf16(a, b1, acc1, 0, 0, 0);
        }
        #pragma unroll
        for (int r2 = 0; r2 < 4; ++r2) {
            int tb = mt * 16 + g4 * 4 + r2;
            g1[((size_t)tb * 256 + blk) * 32 + r]      = acc0[r2] + b1_lds[r];      // block-private: plain
            g1[((size_t)tb * 256 + blk) * 32 + 16 + r] = acc1[r2] + b1_lds[16 + r];
        }
    }
    __syncthreads();
    load_w_lds(smem, w_hh1, blk, tid);   // L3-warm after touch
    __syncthreads();

    // ---------- layer 1 recurrence ----------
    float c1 = 0.f;
    for (int t = 0; t < TT; ++t) {
        const __hip_bfloat16* hp = h1_ws + (size_t)((t > 0 ? t - 1 : 0) * BB * HH);
        step_gemm(hp, smem, gparts, lane, wv, t > 0);
        __syncthreads();
        if (tid < 256) {
            float gv[4];
            #pragma unroll
            for (int gate = 0; gate < 4; ++gate) {
                int n = gate * 8 + u;
                gv[gate] = gparts[m * 33 + n] + gparts[(32 + m) * 33 + n]
                         + g1[((size_t)(t * 32 + m) * 256 + blk) * 32 + n];
            }
            float ig = sigm(gv[0]), fg = sigm(gv[1]), g2 = tanhf(gv[2]), og = sigm(gv[3]);
            c1 = fg * c1 + ig * g2;
            store_h(h1_ws + (size_t)(t * 32 + m) * 2048 + blk * 8 + u, og * tanhf(c1));
        }
        gbar_arrive(ws, 4 + t, blk);
        gbar_wait(ws, 4 + t);
    }

    // ---------- final linear + sigmoid ----------
    if (blk < BB) {
        float part = 0.f;
        for (int i = tid; i < 1024; i += NTHR) {     // 1024 chunks of 8 bf16
            int k = i * 8; int t = k >> 11; int uu = k & 2047;
            uint4 hv = *reinterpret_cast<const uint4*>(h1_ws + (size_t)(t * 32 + blk) * 2048 + uu);
            const float* lw = lin_w + k;
            #pragma unroll
            for (int j = 0; j < 4; ++j) {
                unsigned wj = (&hv.x)[j];
                float lo = __uint_as_float(wj << 16);
                float hi = __uint_as_float(wj & 0xffff0000u);
                part += lo * lw[2 * j] + hi * lw[2 * j + 1];
            }
        }
        #pragma unroll
        for (int off = 32; off; off >>= 1) part += __shfl_down(part, off, 64);
        if (lane == 0) red[wv] = part;
        __syncthreads();
        if (tid == 0) {
            float s = red[0] + red[1] + red[2] + red[3] + red[4] + red[5] + red[6] + red[7] + lin_b[0];
            out[blk] = 1.f / (1.f + expf(-s));
        }
    }
}

extern "C" void kernel_launch(void* const* d_in, const int* in_sizes, int n_in,
                              void* d_out, int out_size, void* d_ws, size_t ws_size,
                              hipStream_t stream) {
    const float* state  = (const float*)d_in[0];
    const float* action = (const float*)d_in[1];
    const float* conv_w = (const float*)d_in[2];
    const float* conv_b = (const float*)d_in[3];
    const float* w_ih0  = (const float*)d_in[4];
    const float* w_hh0  = (const float*)d_in[5];
    const float* b_ih0  = (const float*)d_in[6];
    const float* b_hh0  = (const float*)d_in[7];
    const float* w_ih1  = (const float*)d_in[8];
    const float* w_hh1  = (const float*)d_in[9];
    const float* b_ih1  = (const float*)d_in[10];
    const float* b_hh1  = (const float*)d_in[11];
    const float* lin_w  = (const float*)d_in[12];
    const float* lin_b  = (const float*)d_in[13];
    float* out = (float*)d_out;
    char*  ws  = (char*)d_ws;

    hipMemsetAsync(ws, 0, BAR_BYTES, stream);   // zero barrier slots (graph-capturable)

    void* args[] = {&state, &action, &conv_w, &conv_b, &w_ih0, &w_hh0, &b_ih0, &b_hh0,
                    &w_ih1, &w_hh1, &b_ih1, &b_hh1, &lin_w, &lin_b, &out, &ws};
    hipLaunchCooperativeKernel((void*)fused_lstm, dim3(NBLK), dim3(NTHR), args,
                               LDS_TOTAL, stream);
}

// Round 4
// 297.457 us; speedup vs baseline: 2.2397x; 1.1842x over previous
//
#include <hip/hip_runtime.h>
#include <hip/hip_bf16.h>
#include <math.h>

typedef __bf16 bf16_t;
typedef bf16_t bf16x8 __attribute__((ext_vector_type(8)));
typedef bf16_t bf16x4 __attribute__((ext_vector_type(4)));
typedef float  f32x4  __attribute__((ext_vector_type(4)));
typedef float  vf4    __attribute__((ext_vector_type(4)));

#define HH 2048
#define BB 32
#define TT 4
#define FF 19
#define NBLK 256
#define NTHR 512

// ---- dynamic LDS layout (bytes) ----
#define LDS_WHH   0         // bf16[32][2048] swizzled : 131072
#define LDS_X     131072    // float[128][20]          : 10240
#define LDS_WIH0  141312    // float[32][20]           : 2560
#define LDS_B0    143872    // float[32]               : 128
#define LDS_B1    144000    // float[32]               : 128
#define LDS_GP    144128    // float[2][32][33]        : 8448
#define LDS_RED   152576    // float[8]                : 32
#define LDS_TOTAL 152608

// ---- workspace layout (bytes) ----
#define WS_BAR    0         // 8 barrier slots x 1024 B (memset 0 each launch)
#define BAR_BYTES 8192
#define WS_H0     16384     // bf16 [T*B][2048] : 524288
#define WS_H1     540672    // bf16 [T*B][2048] : 524288
#define WS_G1     1064960   // f32 [128][256][32] : 4194304  (end 5259264)

__device__ __forceinline__ float sigm(float x) { return 1.0f / (1.0f + expf(-x)); }

// ---- fence-free two-level grid barrier (see R3 notes) ----
// Safe without __threadfence: h-stores are write-through agent atomics drained
// by the vmcnt(0) that __syncthreads emits; every h region is written once and
// read only post-barrier, and no XCD L2 can hold a pre-barrier copy.
__device__ __forceinline__ void gbar_arrive(char* barbase, int slot, int blk) {
    __syncthreads();   // drains all vector stores (compiler emits vmcnt(0))
    if (threadIdx.x == 0) {
        unsigned* base = (unsigned*)(barbase + slot * 1024);
        if (__hip_atomic_fetch_add(base + (blk & 7) * 16, 1u, __ATOMIC_RELAXED, __HIP_MEMORY_SCOPE_AGENT) == 31u)
            if (__hip_atomic_fetch_add(base + 128, 1u, __ATOMIC_RELAXED, __HIP_MEMORY_SCOPE_AGENT) == 7u)
                __hip_atomic_store(base + 144, 1u, __ATOMIC_RELAXED, __HIP_MEMORY_SCOPE_AGENT);
    }
}
__device__ __forceinline__ void gbar_wait(char* barbase, int slot) {
    if (threadIdx.x == 0) {
        unsigned* flag = (unsigned*)(barbase + slot * 1024) + 144;
        while (__hip_atomic_load(flag, __ATOMIC_RELAXED, __HIP_MEMORY_SCOPE_AGENT) == 0u)
            __builtin_amdgcn_s_sleep(1);
    }
    __syncthreads();
}

// Load 32 gate-rows x 2048 f32 -> bf16 LDS, XOR-swizzled byte ^= ((row&7)<<4).
// Block-local: legal (and intended) to run between gbar_arrive and gbar_wait.
__device__ __forceinline__ void load_w_lds(char* smem, const float* __restrict__ w, int blk, int tid) {
    char* dst = smem + LDS_WHH;
    #pragma unroll 1
    for (int base = 0; base < 32; base += 8) {
        vf4 v[8];
        #pragma unroll
        for (int j = 0; j < 8; ++j) {
            int row = base + j;
            int gr = (row >> 3) * 2048 + blk * 8 + (row & 7);
            v[j] = *reinterpret_cast<const vf4*>(w + (size_t)gr * 2048 + tid * 4);
        }
        #pragma unroll
        for (int j = 0; j < 8; ++j) {
            int row = base + j;
            bf16x4 bv;
            bv[0] = (bf16_t)v[j][0]; bv[1] = (bf16_t)v[j][1];
            bv[2] = (bf16_t)v[j][2]; bv[3] = (bf16_t)v[j][3];
            unsigned byte = (unsigned)(row * 4096) + (((unsigned)(tid * 8)) ^ (((unsigned)(row & 7)) << 4));
            *reinterpret_cast<bf16x4*>(dst + byte) = bv;
        }
    }
}

// gates(32x32) = h_prev(32x2048 bf16 global, cached loads) @ w_lds.T
// 8 waves: wave = quadrant(2b) x K-half(1b); partials -> gparts[2][32][33].
__device__ __forceinline__ void step_gemm(const __hip_bfloat16* __restrict__ hprev,
                                          const char* smem, float* gparts,
                                          int lane, int wv) {
    const int q  = wv >> 1;
    const int kh = wv & 1;
    const int mt = q >> 1, nt = q & 1;
    const int r = lane & 15, g4 = lane >> 4;
    f32x4 acc0 = {0.f,0.f,0.f,0.f}, acc1 = {0.f,0.f,0.f,0.f};
    const char* bbase = smem + LDS_WHH;
    const int n = nt * 16 + r;
    const unsigned brow = (unsigned)(n * 4096);
    const unsigned bsw = ((unsigned)(n & 7)) << 4;
    const __hip_bfloat16* aptr = hprev + (mt * 16 + r) * 2048 + g4 * 8;
    const int k0 = kh * 32;
    #pragma unroll
    for (int ks = 0; ks < 32; ks += 2) {
        int ka = k0 + ks, kb = k0 + ks + 1;
        bf16x8 a0 = *reinterpret_cast<const bf16x8*>(aptr + ka * 32);
        bf16x8 b0 = *reinterpret_cast<const bf16x8*>(bbase + brow + (((unsigned)(ka * 64 + g4 * 16)) ^ bsw));
        acc0 = __builtin_amdgcn_mfma_f32_16x16x32_bf16(a0, b0, acc0, 0, 0, 0);
        bf16x8 a1 = *reinterpret_cast<const bf16x8*>(aptr + kb * 32);
        bf16x8 b1 = *reinterpret_cast<const bf16x8*>(bbase + brow + (((unsigned)(kb * 64 + g4 * 16)) ^ bsw));
        acc1 = __builtin_amdgcn_mfma_f32_16x16x32_bf16(a1, b1, acc1, 0, 0, 0);
    }
    f32x4 s = acc0 + acc1;
    #pragma unroll
    for (int r2 = 0; r2 < 4; ++r2)  // D map: col=lane&15, row=(lane>>4)*4+reg
        gparts[(kh * 32 + mt * 16 + g4 * 4 + r2) * 33 + nt * 16 + r] = s[r2];
}

// write-through agent-scope bf16 store
__device__ __forceinline__ void store_h(__hip_bfloat16* p, float x) {
    __hip_bfloat16 hv = __float2bfloat16(x);
    unsigned short bits = *reinterpret_cast<unsigned short*>(&hv);
    __hip_atomic_store((unsigned short*)p, bits, __ATOMIC_RELAXED, __HIP_MEMORY_SCOPE_AGENT);
}

__global__ __launch_bounds__(NTHR, 2) void fused_lstm(
    const float* __restrict__ state, const float* __restrict__ action,
    const float* __restrict__ conv_w, const float* __restrict__ conv_b,
    const float* __restrict__ w_ih0, const float* __restrict__ w_hh0,
    const float* __restrict__ b_ih0, const float* __restrict__ b_hh0,
    const float* __restrict__ w_ih1, const float* __restrict__ w_hh1,
    const float* __restrict__ b_ih1, const float* __restrict__ b_hh1,
    const float* __restrict__ lin_w, const float* __restrict__ lin_b,
    float* __restrict__ out, char* __restrict__ ws)
{
    extern __shared__ char smem[];
    float* x_lds    = (float*)(smem + LDS_X);
    float* wih0_lds = (float*)(smem + LDS_WIH0);
    float* b0_lds   = (float*)(smem + LDS_B0);
    float* b1_lds   = (float*)(smem + LDS_B1);
    float* gparts   = (float*)(smem + LDS_GP);
    float* red      = (float*)(smem + LDS_RED);

    const int tid  = threadIdx.x;
    const int blk  = blockIdx.x;
    const int lane = tid & 63;
    const int wv   = tid >> 6;
    const int m    = tid >> 3;   // (tid<256) batch row owned in gate phase
    const int u    = tid & 7;    // (tid<256) local hidden unit owned

    __hip_bfloat16* h0_ws = (__hip_bfloat16*)(ws + WS_H0);
    __hip_bfloat16* h1_ws = (__hip_bfloat16*)(ws + WS_H1);
    float*          g1    = (float*)(ws + WS_G1);

    // ---------- prep: x = tanh(cw*concat(state,action)+cb), w_ih0 slice, bias0 ----------
    {
        float cw = conv_w[0], cb = conv_b[0];
        for (int i = tid; i < TT * BB * FF; i += NTHR) {
            int f = i % FF; int tb = i / FF; int t = tb >> 5; int mm = tb & 31;
            float v = (f < 15) ? state[(mm * TT + t) * 15 + f] : action[(mm * TT + t) * 4 + (f - 15)];
            x_lds[tb * 20 + f] = tanhf(cw * v + cb);
        }
        for (int i = tid; i < 32 * FF; i += NTHR) {
            int n = i / FF; int f = i % FF;
            int gr = (n >> 3) * 2048 + blk * 8 + (n & 7);
            wih0_lds[n * 20 + f] = w_ih0[(size_t)gr * FF + f];
        }
        if (tid < 32) {
            int gr = (tid >> 3) * 2048 + blk * 8 + (tid & 7);
            b0_lds[tid] = b_ih0[gr] + b_hh0[gr];
        }
    }
    __syncthreads();

    // ---------- layer 0, t=0 (no recurrent term) ----------
    float c0 = 0.f;
    if (tid < 256) {
        float gv[4];
        #pragma unroll
        for (int gate = 0; gate < 4; ++gate) {
            int n = gate * 8 + u;
            float a = b0_lds[n];
            const float* xr = &x_lds[m * 20];
            const float* wr = &wih0_lds[n * 20];
            #pragma unroll
            for (int f = 0; f < FF; ++f) a += xr[f] * wr[f];
            gv[gate] = a;
        }
        float ig = sigm(gv[0]), fg = sigm(gv[1]), g2 = tanhf(gv[2]), og = sigm(gv[3]);
        c0 = fg * c0 + ig * g2;
        store_h(h0_ws + (size_t)m * 2048 + blk * 8 + u, og * tanhf(c0));
    }
    gbar_arrive(ws, 0, blk);
    load_w_lds(smem, w_hh0, blk, tid);   // staged in barrier slack
    gbar_wait(ws, 0);

    // ---------- layer 0, t=1..3 ----------
    for (int t = 1; t < TT; ++t) {
        step_gemm(h0_ws + (size_t)(t - 1) * BB * HH, smem, gparts, lane, wv);
        __syncthreads();
        if (tid < 256) {
            float gv[4];
            #pragma unroll
            for (int gate = 0; gate < 4; ++gate) {
                int n = gate * 8 + u;
                float a = gparts[m * 33 + n] + gparts[(32 + m) * 33 + n] + b0_lds[n];
                const float* xr = &x_lds[(t * 32 + m) * 20];
                const float* wr = &wih0_lds[n * 20];
                #pragma unroll
                for (int f = 0; f < FF; ++f) a += xr[f] * wr[f];
                gv[gate] = a;
            }
            float ig = sigm(gv[0]), fg = sigm(gv[1]), g2 = tanhf(gv[2]), og = sigm(gv[3]);
            c0 = fg * c0 + ig * g2;
            store_h(h0_ws + (size_t)(t * 32 + m) * 2048 + blk * 8 + u, og * tanhf(c0));
        }
        gbar_arrive(ws, t, blk);
        if (t == 3) {   // stage w_ih1 + bias1 in the last layer-0 barrier's slack
            load_w_lds(smem, w_ih1, blk, tid);
            if (tid < 32) {
                int gr = (tid >> 3) * 2048 + blk * 8 + (tid & 7);
                b1_lds[tid] = b_ih1[gr] + b_hh1[gr];
            }
        }
        gbar_wait(ws, t);
    }

    // ---------- layer-1 input GEMM: g1 = H0(128x2048) @ w_ih1_slice.T + bias1 ----------
    {
        const int r = lane & 15, g4 = lane >> 4;
        const char* bbase = smem + LDS_WHH;
        const unsigned bsw0 = ((unsigned)(r & 7)) << 4;   // rows r and 16+r share (row&7)
        const int mt = wv;                                 // 8 waves -> 8 m-tiles of 16
        f32x4 acc0 = {0.f,0.f,0.f,0.f}, acc1 = {0.f,0.f,0.f,0.f};
        const __hip_bfloat16* aptr = h0_ws + (size_t)(mt * 16 + r) * 2048 + g4 * 8;
        #pragma unroll 4
        for (int ks = 0; ks < 64; ++ks) {
            bf16x8 a  = *reinterpret_cast<const bf16x8*>(aptr + ks * 32);
            bf16x8 b0 = *reinterpret_cast<const bf16x8*>(bbase + (unsigned)(r * 4096)        + (((unsigned)(ks * 64 + g4 * 16)) ^ bsw0));
            bf16x8 b1 = *reinterpret_cast<const bf16x8*>(bbase + (unsigned)((16 + r) * 4096) + (((unsigned)(ks * 64 + g4 * 16)) ^ bsw0));
            acc0 = __builtin_amdgcn_mfma_f32_16x16x32_bf16(a, b0, acc0, 0, 0, 0);
            acc1 = __builtin_amdgcn_mfma_f32_16x16x32_bf16(a, b1, acc1, 0, 0, 0);
        }
        #pragma unroll
        for (int r2 = 0; r2 < 4; ++r2) {
            int tb = mt * 16 + g4 * 4 + r2;
            g1[((size_t)tb * 256 + blk) * 32 + r]      = acc0[r2] + b1_lds[r];      // block-private
            g1[((size_t)tb * 256 + blk) * 32 + 16 + r] = acc1[r2] + b1_lds[16 + r];
        }
    }
    __syncthreads();   // drains g1 stores (vmcnt 0) before same-block reads

    // ---------- layer 1, t=0 (no recurrent term) ----------
    float c1 = 0.f;
    if (tid < 256) {
        float gv[4];
        #pragma unroll
        for (int gate = 0; gate < 4; ++gate) {
            int n = gate * 8 + u;
            gv[gate] = g1[((size_t)m * 256 + blk) * 32 + n];
        }
        float ig = sigm(gv[0]), fg = sigm(gv[1]), g2 = tanhf(gv[2]), og = sigm(gv[3]);
        c1 = fg * c1 + ig * g2;
        store_h(h1_ws + (size_t)m * 2048 + blk * 8 + u, og * tanhf(c1));
    }
    gbar_arrive(ws, 4, blk);
    load_w_lds(smem, w_hh1, blk, tid);   // staged in barrier slack
    gbar_wait(ws, 4);

    // ---------- layer 1, t=1..3 ----------
    for (int t = 1; t < TT; ++t) {
        step_gemm(h1_ws + (size_t)(t - 1) * BB * HH, smem, gparts, lane, wv);
        __syncthreads();
        if (tid < 256) {
            float gv[4];
            #pragma unroll
            for (int gate = 0; gate < 4; ++gate) {
                int n = gate * 8 + u;
                gv[gate] = gparts[m * 33 + n] + gparts[(32 + m) * 33 + n]
                         + g1[((size_t)(t * 32 + m) * 256 + blk) * 32 + n];
            }
            float ig = sigm(gv[0]), fg = sigm(gv[1]), g2 = tanhf(gv[2]), og = sigm(gv[3]);
            c1 = fg * c1 + ig * g2;
            store_h(h1_ws + (size_t)(t * 32 + m) * 2048 + blk * 8 + u, og * tanhf(c1));
        }
        gbar_arrive(ws, 4 + t, blk);
        gbar_wait(ws, 4 + t);
    }

    // ---------- final linear + sigmoid ----------
    if (blk < BB) {
        float part = 0.f;
        for (int i = tid; i < 1024; i += NTHR) {     // 1024 chunks of 8 bf16
            int k = i * 8; int t = k >> 11; int uu = k & 2047;
            uint4 hv = *reinterpret_cast<const uint4*>(h1_ws + (size_t)(t * 32 + blk) * 2048 + uu);
            const float* lw = lin_w + k;
            #pragma unroll
            for (int j = 0; j < 4; ++j) {
                unsigned wj = (&hv.x)[j];
                float lo = __uint_as_float(wj << 16);
                float hi = __uint_as_float(wj & 0xffff0000u);
                part += lo * lw[2 * j] + hi * lw[2 * j + 1];
            }
        }
        #pragma unroll
        for (int off = 32; off; off >>= 1) part += __shfl_down(part, off, 64);
        if (lane == 0) red[wv] = part;
        __syncthreads();
        if (tid == 0) {
            float s = red[0] + red[1] + red[2] + red[3] + red[4] + red[5] + red[6] + red[7] + lin_b[0];
            out[blk] = 1.f / (1.f + expf(-s));
        }
    }
}

extern "C" void kernel_launch(void* const* d_in, const int* in_sizes, int n_in,
                              void* d_out, int out_size, void* d_ws, size_t ws_size,
                              hipStream_t stream) {
    const float* state  = (const float*)d_in[0];
    const float* action = (const float*)d_in[1];
    const float* conv_w = (const float*)d_in[2];
    const float* conv_b = (const float*)d_in[3];
    const float* w_ih0  = (const float*)d_in[4];
    const float* w_hh0  = (const float*)d_in[5];
    const float* b_ih0  = (const float*)d_in[6];
    const float* b_hh0  = (const float*)d_in[7];
    const float* w_ih1  = (const float*)d_in[8];
    const float* w_hh1  = (const float*)d_in[9];
    const float* b_ih1  = (const float*)d_in[10];
    const float* b_hh1  = (const float*)d_in[11];
    const float* lin_w  = (const float*)d_in[12];
    const float* lin_b  = (const float*)d_in[13];
    float* out = (float*)d_out;
    char*  ws  = (char*)d_ws;

    hipMemsetAsync(ws, 0, BAR_BYTES, stream);   // zero barrier slots

    // Plain (non-cooperative) launch: grid == 256 == #CUs, 152 KiB LDS forces
    // 1 block/CU, so all blocks are co-resident and the ws-based barrier is safe.
    hipLaunchKernelGGL(fused_lstm, dim3(NBLK), dim3(NTHR), LDS_TOTAL, stream,
                       state, action, conv_w, conv_b, w_ih0, w_hh0, b_ih0, b_hh0,
                       w_ih1, w_hh1, b_ih1, b_hh1, lin_w, lin_b, out, ws);
}

// Round 5
// 292.673 us; speedup vs baseline: 2.2763x; 1.0163x over previous
//
#include <hip/hip_runtime.h>
#include <hip/hip_bf16.h>
#include <math.h>

typedef __bf16 bf16_t;
typedef bf16_t bf16x8 __attribute__((ext_vector_type(8)));
typedef bf16_t bf16x4 __attribute__((ext_vector_type(4)));
typedef float  f32x4  __attribute__((ext_vector_type(4)));
typedef float  vf4    __attribute__((ext_vector_type(4)));

#define HH 2048
#define BB 32
#define TT 4
#define FF 19
#define NBLK 256
#define NTHR 512

// ---- dynamic LDS layout (bytes) ----
#define LDS_WHH   0         // bf16[32][2048] swizzled : 131072
#define LDS_X     131072    // float[128][20]          : 10240
#define LDS_WIH0  141312    // float[32][20]           : 2560
#define LDS_B0    143872    // float[32]               : 128
#define LDS_B1    144000    // float[32]               : 128
#define LDS_GP    144128    // float[2][32][33]        : 8448
#define LDS_RED   152576    // float[8]                : 32
#define LDS_TOTAL 152608

// ---- workspace layout (bytes) ----
// Barrier header: 8 slots x 1024 B (8 leaf counters @64B spacing + root @512).
// Broadcast: 8 group lines x 128 B at +8192, monotonic values (slot+1).
#define WS_BCAST  8192
#define BAR_BYTES 12288     // memset to 0 each launch
#define WS_H0     16384     // bf16 [T*B][2048] : 524288
#define WS_H1     540672    // bf16 [T*B][2048] : 524288
#define WS_G1     1064960   // f32 [128][256][32] : 4194304  (end 5259264)

__device__ __forceinline__ float sigm(float x) { return 1.0f / (1.0f + expf(-x)); }

// ---- fence-free two-level grid barrier, low-contention release ----
// Arrival: 32 blocks -> leaf line, 8 leaves -> root (all on distinct lines).
// Release: root-finisher stores (slot+1) to 8 broadcast lines (128 B apart);
// each block's leader spins on ITS GROUP's line only (32 spinners/line, one
// access per ~10 ns aggregate -- far below L3 line service rate; the previous
// single-flag design had 256 spinners on one line and saturated it).
// No __threadfence needed: h-stores are write-through agent atomics drained by
// the vmcnt(0) that __syncthreads emits; h regions are written once and read
// only post-barrier, so no XCD cache can hold a stale pre-barrier copy.
__device__ __forceinline__ void gbar_arrive(char* barbase, int slot, int blk) {
    __syncthreads();   // drains all vector stores (compiler emits vmcnt(0))
    if (threadIdx.x == 0) {
        unsigned* base = (unsigned*)(barbase + slot * 1024);
        if (__hip_atomic_fetch_add(base + (blk & 7) * 16, 1u, __ATOMIC_RELAXED, __HIP_MEMORY_SCOPE_AGENT) == 31u)
            if (__hip_atomic_fetch_add(base + 128, 1u, __ATOMIC_RELAXED, __HIP_MEMORY_SCOPE_AGENT) == 7u) {
                unsigned* bc = (unsigned*)(barbase + WS_BCAST);
                #pragma unroll
                for (int g = 0; g < 8; ++g)
                    __hip_atomic_store(bc + g * 32, (unsigned)(slot + 1), __ATOMIC_RELAXED, __HIP_MEMORY_SCOPE_AGENT);
            }
    }
}
__device__ __forceinline__ void gbar_wait(char* barbase, int slot, int blk) {
    if (threadIdx.x == 0) {
        unsigned* line = (unsigned*)(barbase + WS_BCAST) + (blk & 7) * 32;
        while (__hip_atomic_load(line, __ATOMIC_RELAXED, __HIP_MEMORY_SCOPE_AGENT) < (unsigned)(slot + 1))
            __builtin_amdgcn_s_sleep(1);
    }
    __syncthreads();
}

// Load 32 gate-rows x 2048 f32 -> bf16 LDS, XOR-swizzled byte ^= ((row&7)<<4).
// Block-local: legal (and intended) to run between gbar_arrive and gbar_wait.
__device__ __forceinline__ void load_w_lds(char* smem, const float* __restrict__ w, int blk, int tid) {
    char* dst = smem + LDS_WHH;
    #pragma unroll 1
    for (int base = 0; base < 32; base += 8) {
        vf4 v[8];
        #pragma unroll
        for (int j = 0; j < 8; ++j) {
            int row = base + j;
            int gr = (row >> 3) * 2048 + blk * 8 + (row & 7);
            v[j] = *reinterpret_cast<const vf4*>(w + (size_t)gr * 2048 + tid * 4);
        }
        #pragma unroll
        for (int j = 0; j < 8; ++j) {
            int row = base + j;
            bf16x4 bv;
            bv[0] = (bf16_t)v[j][0]; bv[1] = (bf16_t)v[j][1];
            bv[2] = (bf16_t)v[j][2]; bv[3] = (bf16_t)v[j][3];
            unsigned byte = (unsigned)(row * 4096) + (((unsigned)(tid * 8)) ^ (((unsigned)(row & 7)) << 4));
            *reinterpret_cast<bf16x4*>(dst + byte) = bv;
        }
    }
}

// gates(32x32) = h_prev(32x2048 bf16 global, cached loads) @ w_lds.T
// 8 waves: wave = quadrant(2b) x K-half(1b); partials -> gparts[2][32][33].
__device__ __forceinline__ void step_gemm(const __hip_bfloat16* __restrict__ hprev,
                                          const char* smem, float* gparts,
                                          int lane, int wv) {
    const int q  = wv >> 1;
    const int kh = wv & 1;
    const int mt = q >> 1, nt = q & 1;
    const int r = lane & 15, g4 = lane >> 4;
    f32x4 acc0 = {0.f,0.f,0.f,0.f}, acc1 = {0.f,0.f,0.f,0.f};
    const char* bbase = smem + LDS_WHH;
    const int n = nt * 16 + r;
    const unsigned brow = (unsigned)(n * 4096);
    const unsigned bsw = ((unsigned)(n & 7)) << 4;
    const __hip_bfloat16* aptr = hprev + (mt * 16 + r) * 2048 + g4 * 8;
    const int k0 = kh * 32;
    #pragma unroll
    for (int ks = 0; ks < 32; ks += 2) {
        int ka = k0 + ks, kb = k0 + ks + 1;
        bf16x8 a0 = *reinterpret_cast<const bf16x8*>(aptr + ka * 32);
        bf16x8 b0 = *reinterpret_cast<const bf16x8*>(bbase + brow + (((unsigned)(ka * 64 + g4 * 16)) ^ bsw));
        acc0 = __builtin_amdgcn_mfma_f32_16x16x32_bf16(a0, b0, acc0, 0, 0, 0);
        bf16x8 a1 = *reinterpret_cast<const bf16x8*>(aptr + kb * 32);
        bf16x8 b1 = *reinterpret_cast<const bf16x8*>(bbase + brow + (((unsigned)(kb * 64 + g4 * 16)) ^ bsw));
        acc1 = __builtin_amdgcn_mfma_f32_16x16x32_bf16(a1, b1, acc1, 0, 0, 0);
    }
    f32x4 s = acc0 + acc1;
    #pragma unroll
    for (int r2 = 0; r2 < 4; ++r2)  // D map: col=lane&15, row=(lane>>4)*4+reg
        gparts[(kh * 32 + mt * 16 + g4 * 4 + r2) * 33 + nt * 16 + r] = s[r2];
}

// write-through agent-scope bf16 store
__device__ __forceinline__ void store_h(__hip_bfloat16* p, float x) {
    __hip_bfloat16 hv = __float2bfloat16(x);
    unsigned short bits = *reinterpret_cast<unsigned short*>(&hv);
    __hip_atomic_store((unsigned short*)p, bits, __ATOMIC_RELAXED, __HIP_MEMORY_SCOPE_AGENT);
}

__global__ __launch_bounds__(NTHR, 2) void fused_lstm(
    const float* __restrict__ state, const float* __restrict__ action,
    const float* __restrict__ conv_w, const float* __restrict__ conv_b,
    const float* __restrict__ w_ih0, const float* __restrict__ w_hh0,
    const float* __restrict__ b_ih0, const float* __restrict__ b_hh0,
    const float* __restrict__ w_ih1, const float* __restrict__ w_hh1,
    const float* __restrict__ b_ih1, const float* __restrict__ b_hh1,
    const float* __restrict__ lin_w, const float* __restrict__ lin_b,
    float* __restrict__ out, char* __restrict__ ws)
{
    extern __shared__ char smem[];
    float* x_lds    = (float*)(smem + LDS_X);
    float* wih0_lds = (float*)(smem + LDS_WIH0);
    float* b0_lds   = (float*)(smem + LDS_B0);
    float* b1_lds   = (float*)(smem + LDS_B1);
    float* gparts   = (float*)(smem + LDS_GP);
    float* red      = (float*)(smem + LDS_RED);

    const int tid  = threadIdx.x;
    const int blk  = blockIdx.x;
    const int lane = tid & 63;
    const int wv   = tid >> 6;
    const int m    = tid >> 3;   // (tid<256) batch row owned in gate phase
    const int u    = tid & 7;    // (tid<256) local hidden unit owned

    __hip_bfloat16* h0_ws = (__hip_bfloat16*)(ws + WS_H0);
    __hip_bfloat16* h1_ws = (__hip_bfloat16*)(ws + WS_H1);
    float*          g1    = (float*)(ws + WS_G1);

    // ---------- prep: x = tanh(cw*concat(state,action)+cb), w_ih0 slice, bias0 ----------
    {
        float cw = conv_w[0], cb = conv_b[0];
        for (int i = tid; i < TT * BB * FF; i += NTHR) {
            int f = i % FF; int tb = i / FF; int t = tb >> 5; int mm = tb & 31;
            float v = (f < 15) ? state[(mm * TT + t) * 15 + f] : action[(mm * TT + t) * 4 + (f - 15)];
            x_lds[tb * 20 + f] = tanhf(cw * v + cb);
        }
        for (int i = tid; i < 32 * FF; i += NTHR) {
            int n = i / FF; int f = i % FF;
            int gr = (n >> 3) * 2048 + blk * 8 + (n & 7);
            wih0_lds[n * 20 + f] = w_ih0[(size_t)gr * FF + f];
        }
        if (tid < 32) {
            int gr = (tid >> 3) * 2048 + blk * 8 + (tid & 7);
            b0_lds[tid] = b_ih0[gr] + b_hh0[gr];
        }
    }
    __syncthreads();

    // ---------- layer 0, t=0 (no recurrent term) ----------
    float c0 = 0.f;
    if (tid < 256) {
        float gv[4];
        #pragma unroll
        for (int gate = 0; gate < 4; ++gate) {
            int n = gate * 8 + u;
            float a = b0_lds[n];
            const float* xr = &x_lds[m * 20];
            const float* wr = &wih0_lds[n * 20];
            #pragma unroll
            for (int f = 0; f < FF; ++f) a += xr[f] * wr[f];
            gv[gate] = a;
        }
        float ig = sigm(gv[0]), fg = sigm(gv[1]), g2 = tanhf(gv[2]), og = sigm(gv[3]);
        c0 = fg * c0 + ig * g2;
        store_h(h0_ws + (size_t)m * 2048 + blk * 8 + u, og * tanhf(c0));
    }
    gbar_arrive(ws, 0, blk);
    load_w_lds(smem, w_hh0, blk, tid);   // staged in barrier slack
    gbar_wait(ws, 0, blk);

    // ---------- layer 0, t=1..3 ----------
    for (int t = 1; t < TT; ++t) {
        step_gemm(h0_ws + (size_t)(t - 1) * BB * HH, smem, gparts, lane, wv);
        __syncthreads();
        if (tid < 256) {
            float gv[4];
            #pragma unroll
            for (int gate = 0; gate < 4; ++gate) {
                int n = gate * 8 + u;
                float a = gparts[m * 33 + n] + gparts[(32 + m) * 33 + n] + b0_lds[n];
                const float* xr = &x_lds[(t * 32 + m) * 20];
                const float* wr = &wih0_lds[n * 20];
                #pragma unroll
                for (int f = 0; f < FF; ++f) a += xr[f] * wr[f];
                gv[gate] = a;
            }
            float ig = sigm(gv[0]), fg = sigm(gv[1]), g2 = tanhf(gv[2]), og = sigm(gv[3]);
            c0 = fg * c0 + ig * g2;
            store_h(h0_ws + (size_t)(t * 32 + m) * 2048 + blk * 8 + u, og * tanhf(c0));
        }
        gbar_arrive(ws, t, blk);
        if (t == 3) {   // stage w_ih1 + bias1 in the last layer-0 barrier's slack
            load_w_lds(smem, w_ih1, blk, tid);
            if (tid < 32) {
                int gr = (tid >> 3) * 2048 + blk * 8 + (tid & 7);
                b1_lds[tid] = b_ih1[gr] + b_hh1[gr];
            }
        }
        gbar_wait(ws, t, blk);
    }

    // ---------- layer-1 input GEMM: g1 = H0(128x2048) @ w_ih1_slice.T + bias1 ----------
    {
        const int r = lane & 15, g4 = lane >> 4;
        const char* bbase = smem + LDS_WHH;
        const unsigned bsw0 = ((unsigned)(r & 7)) << 4;   // rows r and 16+r share (row&7)
        const int mt = wv;                                 // 8 waves -> 8 m-tiles of 16
        f32x4 acc0 = {0.f,0.f,0.f,0.f}, acc1 = {0.f,0.f,0.f,0.f};
        const __hip_bfloat16* aptr = h0_ws + (size_t)(mt * 16 + r) * 2048 + g4 * 8;
        #pragma unroll 4
        for (int ks = 0; ks < 64; ++ks) {
            bf16x8 a  = *reinterpret_cast<const bf16x8*>(aptr + ks * 32);
            bf16x8 b0 = *reinterpret_cast<const bf16x8*>(bbase + (unsigned)(r * 4096)        + (((unsigned)(ks * 64 + g4 * 16)) ^ bsw0));
            bf16x8 b1 = *reinterpret_cast<const bf16x8*>(bbase + (unsigned)((16 + r) * 4096) + (((unsigned)(ks * 64 + g4 * 16)) ^ bsw0));
            acc0 = __builtin_amdgcn_mfma_f32_16x16x32_bf16(a, b0, acc0, 0, 0, 0);
            acc1 = __builtin_amdgcn_mfma_f32_16x16x32_bf16(a, b1, acc1, 0, 0, 0);
        }
        #pragma unroll
        for (int r2 = 0; r2 < 4; ++r2) {
            int tb = mt * 16 + g4 * 4 + r2;
            g1[((size_t)tb * 256 + blk) * 32 + r]      = acc0[r2] + b1_lds[r];      // block-private
            g1[((size_t)tb * 256 + blk) * 32 + 16 + r] = acc1[r2] + b1_lds[16 + r];
        }
    }
    __syncthreads();   // drains g1 stores (vmcnt 0) before same-block reads

    // ---------- layer 1, t=0 (no recurrent term) ----------
    float c1 = 0.f;
    if (tid < 256) {
        float gv[4];
        #pragma unroll
        for (int gate = 0; gate < 4; ++gate) {
            int n = gate * 8 + u;
            gv[gate] = g1[((size_t)m * 256 + blk) * 32 + n];
        }
        float ig = sigm(gv[0]), fg = sigm(gv[1]), g2 = tanhf(gv[2]), og = sigm(gv[3]);
        c1 = fg * c1 + ig * g2;
        store_h(h1_ws + (size_t)m * 2048 + blk * 8 + u, og * tanhf(c1));
    }
    gbar_arrive(ws, 4, blk);
    load_w_lds(smem, w_hh1, blk, tid);   // staged in barrier slack
    gbar_wait(ws, 4, blk);

    // ---------- layer 1, t=1..3 ----------
    for (int t = 1; t < TT; ++t) {
        step_gemm(h1_ws + (size_t)(t - 1) * BB * HH, smem, gparts, lane, wv);
        __syncthreads();
        if (tid < 256) {
            float gv[4];
            #pragma unroll
            for (int gate = 0; gate < 4; ++gate) {
                int n = gate * 8 + u;
                gv[gate] = gparts[m * 33 + n] + gparts[(32 + m) * 33 + n]
                         + g1[((size_t)(t * 32 + m) * 256 + blk) * 32 + n];
            }
            float ig = sigm(gv[0]), fg = sigm(gv[1]), g2 = tanhf(gv[2]), og = sigm(gv[3]);
            c1 = fg * c1 + ig * g2;
            store_h(h1_ws + (size_t)(t * 32 + m) * 2048 + blk * 8 + u, og * tanhf(c1));
        }
        gbar_arrive(ws, 4 + t, blk);
        gbar_wait(ws, 4 + t, blk);
    }

    // ---------- final linear + sigmoid ----------
    if (blk < BB) {
        float part = 0.f;
        for (int i = tid; i < 1024; i += NTHR) {     // 1024 chunks of 8 bf16
            int k = i * 8; int t = k >> 11; int uu = k & 2047;
            uint4 hv = *reinterpret_cast<const uint4*>(h1_ws + (size_t)(t * 32 + blk) * 2048 + uu);
            const float* lw = lin_w + k;
            #pragma unroll
            for (int j = 0; j < 4; ++j) {
                unsigned wj = (&hv.x)[j];
                float lo = __uint_as_float(wj << 16);
                float hi = __uint_as_float(wj & 0xffff0000u);
                part += lo * lw[2 * j] + hi * lw[2 * j + 1];
            }
        }
        #pragma unroll
        for (int off = 32; off; off >>= 1) part += __shfl_down(part, off, 64);
        if (lane == 0) red[wv] = part;
        __syncthreads();
        if (tid == 0) {
            float s = red[0] + red[1] + red[2] + red[3] + red[4] + red[5] + red[6] + red[7] + lin_b[0];
            out[blk] = 1.f / (1.f + expf(-s));
        }
    }
}

extern "C" void kernel_launch(void* const* d_in, const int* in_sizes, int n_in,
                              void* d_out, int out_size, void* d_ws, size_t ws_size,
                              hipStream_t stream) {
    const float* state  = (const float*)d_in[0];
    const float* action = (const float*)d_in[1];
    const float* conv_w = (const float*)d_in[2];
    const float* conv_b = (const float*)d_in[3];
    const float* w_ih0  = (const float*)d_in[4];
    const float* w_hh0  = (const float*)d_in[5];
    const float* b_ih0  = (const float*)d_in[6];
    const float* b_hh0  = (const float*)d_in[7];
    const float* w_ih1  = (const float*)d_in[8];
    const float* w_hh1  = (const float*)d_in[9];
    const float* b_ih1  = (const float*)d_in[10];
    const float* b_hh1  = (const float*)d_in[11];
    const float* lin_w  = (const float*)d_in[12];
    const float* lin_b  = (const float*)d_in[13];
    float* out = (float*)d_out;
    char*  ws  = (char*)d_ws;

    hipMemsetAsync(ws, 0, BAR_BYTES, stream);   // zero barrier header + broadcast lines

    // Plain (non-cooperative) launch: grid == 256 == #CUs, 152 KiB LDS forces
    // 1 block/CU, so all blocks are co-resident and the ws-based barrier is safe.
    hipLaunchKernelGGL(fused_lstm, dim3(NBLK), dim3(NTHR), LDS_TOTAL, stream,
                       state, action, conv_w, conv_b, w_ih0, w_hh0, b_ih0, b_hh0,
                       w_ih1, w_hh1, b_ih1, b_hh1, lin_w, lin_b, out, ws);
}